// Round 13
// baseline (658.941 us; speedup 1.0000x reference)
//
#include <hip/hip_runtime.h>
#include <float.h>

#define N_PTS 262144
#define K_CL  1024
#define D     64
#define PTS_PER_WAVE   64
#define WAVES_PER_BLK  16
#define PTS_PER_BLK    (PTS_PER_WAVE * WAVES_PER_BLK)   // 1024
#define NTILE 8
#define MARGIN_S 0.5f        // score margin (distance margin 1.0; fp16 err bound ~0.1)
#define CAP 4                // top-4 reservoir per point-slot

typedef _Float16 f16;
typedef _Float16 half8 __attribute__((ext_vector_type(8)));
typedef float    f32x4 __attribute__((ext_vector_type(4)));

// ---- prep: csq (exact fp32), csqhn = -0.5*csq, cent16 = fp16 PRE-SWIZZLED
__global__ __launch_bounds__(256) void prep_kernel(const float* __restrict__ cent,
                                                   float* __restrict__ csq,
                                                   float* __restrict__ csqhn,
                                                   f16* __restrict__ cent16) {
    int k = blockIdx.x * 256 + threadIdx.x;
    if (k >= K_CL) return;
    const float* row = &cent[(size_t)k * D];
    float s = 0.f;
    #pragma unroll
    for (int d = 0; d < D; ++d) s = fmaf(row[d], row[d], s);
    csq[k]   = s;
    csqhn[k] = -0.5f * s;
    int sw = k & 7;
    #pragma unroll
    for (int ch = 0; ch < 8; ++ch) {
        half8 h;
        #pragma unroll
        for (int e = 0; e < 8; ++e) h[e] = (f16)row[ch * 8 + e];
        *reinterpret_cast<half8*>(&cent16[(size_t)k * D + (size_t)((ch ^ sw) * 8)]) = h;
    }
}

__device__ __forceinline__ float exact_dist(const float* __restrict__ xr,
                                            const float* __restrict__ cr,
                                            float xsq, float cs) {
    float dot = 0.f;
    #pragma unroll
    for (int d = 0; d < D; ++d) dot = fmaf(xr[d], cr[d], dot);
    return (xsq - 2.0f * dot) + cs;
}

__device__ __forceinline__ half8 point_frag(const float* __restrict__ batch,
                                            int prow, int chunk) {
    const float* src = &batch[(size_t)prow * D + chunk * 8];
    float4 u0 = *reinterpret_cast<const float4*>(src);
    float4 u1 = *reinterpret_cast<const float4*>(src + 4);
    half8 h;
    h[0] = (f16)u0.x; h[1] = (f16)u0.y; h[2] = (f16)u0.z; h[3] = (f16)u0.w;
    h[4] = (f16)u1.x; h[5] = (f16)u1.y; h[6] = (f16)u1.z; h[7] = (f16)u1.w;
    return h;
}

__device__ __forceinline__ float vmax4(const f32x4& a) {
    return fmaxf(fmaxf(a.x, a.y), fmaxf(a.z, a.w));
}

// top-CAP reservoir insert, min-replacement; all positions static (rule #20).
__device__ __forceinline__ void rins(float sv, int c, int& cnt,
                                     float& s0, float& s1, float& s2, float& s3,
                                     int& i0, int& i1, int& i2, int& i3) {
    if (cnt < CAP) {
        if      (cnt == 0) { s0 = sv; i0 = c; }
        else if (cnt == 1) { s1 = sv; i1 = c; }
        else if (cnt == 2) { s2 = sv; i2 = c; }
        else               { s3 = sv; i3 = c; }
        cnt++;
    } else {
        float mn = s0; int mi = 0;
        if (s1 < mn) { mn = s1; mi = 1; }
        if (s2 < mn) { mn = s2; mi = 2; }
        if (s3 < mn) { mn = s3; mi = 3; }
        if (sv > mn) {   // drop current min (dropped <= reservoir min, which is non-decreasing)
            if      (mi == 0) { s0 = sv; i0 = c; }
            else if (mi == 1) { s1 = sv; i1 = c; }
            else if (mi == 2) { s2 = sv; i2 = c; }
            else              { s3 = sv; i3 = c; }
        }
    }
}

// exact fp32 resolve over reservoir; full-slice fallback iff all CAP survive thrF
// (only case where a within-margin candidate could have been dropped).
__device__ __forceinline__ void resolve_r(const float* __restrict__ batch,
                                          const float* __restrict__ cent,
                                          const float* __restrict__ csq,
                                          int prow, int hi, float thrF, int cnt,
                                          float s0, float s1, float s2, float s3,
                                          int i0, int i1, int i2, int i3,
                                          float& bd, int& bi) {
    bd = FLT_MAX; bi = 0x7fffffff;
    const float* xr = &batch[(size_t)prow * D];
    float xsq = 0.f;
    #pragma unroll
    for (int d = 0; d < D; ++d) xsq = fmaf(xr[d], xr[d], xsq);
    int svc = 0;
    if (cnt > 0 && s0 >= thrF) svc++;
    if (cnt > 1 && s1 >= thrF) svc++;
    if (cnt > 2 && s2 >= thrF) svc++;
    if (cnt > 3 && s3 >= thrF) svc++;
    if (svc < CAP) {
        #pragma unroll
        for (int r = 0; r < CAP; ++r) {
            int c = (r == 0) ? i0 : (r == 1) ? i1 : (r == 2) ? i2 : i3;
            if (r < cnt) {
                float dd = exact_dist(xr, &cent[(size_t)c * D], xsq, csq[c]);
                if (dd < bd || (dd == bd && c < bi)) { bd = dd; bi = c; }
            }
        }
    } else {  // rare (P~2e-4): exact scan of this lane's row slice
        for (int t16 = 0; t16 < 64; ++t16) {
            #pragma unroll
            for (int r = 0; r < 4; ++r) {
                int c = t16 * 16 + hi * 4 + r;
                float dd = exact_dist(xr, &cent[(size_t)c * D], xsq, csq[c]);
                if (dd < bd || (dd == bd && c < bi)) { bd = dd; bi = c; }
            }
        }
    }
}

// 1024 threads, 16 waves, 1 block/CU; full centroid set in LDS, single barrier.
// SINGLE pass: MFMA scores -> running max + top-4 reservoir -> exact resolve.
// Fused scatter tail: f32 fire-and-forget atomics into nsplit-way partials.
__global__ __launch_bounds__(1024, 4) void assign_kernel(
    const float* __restrict__ batch,
    const f16*   __restrict__ cent16,
    const float* __restrict__ csq,
    const float* __restrict__ csqhn,
    const float* __restrict__ cent,
    float* __restrict__ out_assign,
    float* __restrict__ ps_base,     // [nsplit][K_CL][D] (or out_sums if direct)
    float* __restrict__ cs_base,     // [nsplit][K_CL]    (or out_counts)
    int split_mask)
{
    __shared__ f16   C16[K_CL * D];              // 128 KB, swizzled phys layout
    __shared__ __align__(16) float CH[K_CL];     // 4 KB (-0.5*csq)

    const int tid   = threadIdx.x;
    const int wave  = tid >> 6;
    const int lane  = tid & 63;
    const int lo    = lane & 15;
    const int hi    = lane >> 4;
    const int wbase = (blockIdx.x * WAVES_PER_BLK + wave) * PTS_PER_WAVE;

    #pragma unroll
    for (int it = 0; it < 8; ++it) {
        int u = tid + 1024 * it;
        *reinterpret_cast<half8*>(&C16[u * 8]) =
            *reinterpret_cast<const half8*>(&cent16[(size_t)u * 8]);
    }
    CH[tid] = csqhn[tid];
    __syncthreads();

    const int pr0 = wbase + 0 * 16 + lo;
    const int pr1 = wbase + 1 * 16 + lo;
    const int pr2 = wbase + 2 * 16 + lo;
    const int pr3 = wbase + 3 * 16 + lo;

    const half8 p0a = point_frag(batch, pr0, hi), p0b = point_frag(batch, pr0, 4 + hi);
    const half8 p1a = point_frag(batch, pr1, hi), p1b = point_frag(batch, pr1, 4 + hi);
    const half8 p2a = point_frag(batch, pr2, hi), p2b = point_frag(batch, pr2, 4 + hi);
    const half8 p3a = point_frag(batch, pr3, hi), p3b = point_frag(batch, pr3, 4 + hi);

    // ======== SINGLE PASS: scores + running max + top-4 reservoir ========
    float m0 = -FLT_MAX, m1 = -FLT_MAX, m2 = -FLT_MAX, m3 = -FLT_MAX;
    int   n0 = 0, n1 = 0, n2 = 0, n3 = 0;
    float s00=0,s01=0,s02=0,s03=0, s10=0,s11=0,s12=0,s13=0;
    float s20=0,s21=0,s22=0,s23=0, s30=0,s31=0,s32=0,s33=0;
    int   i00=0,i01=0,i02=0,i03=0, i10=0,i11=0,i12=0,i13=0;
    int   i20=0,i21=0,i22=0,i23=0, i30=0,i31=0,i32=0,i33=0;

    for (int t = 0; t < NTILE; ++t) {
        const int base = t * 128;
        #pragma unroll
        for (int m = 0; m < 8; ++m) {
            const int row = base + m * 16 + lo;
            const int sw  = row & 7;
            const half8 cf0 = *reinterpret_cast<const half8*>(&C16[row * D + ((hi     ^ sw) * 8)]);
            const half8 cf1 = *reinterpret_cast<const half8*>(&C16[row * D + (((4+hi) ^ sw) * 8)]);
            const f32x4 ch  = *reinterpret_cast<const f32x4*>(&CH[base + m * 16 + hi * 4]);
            f32x4 a0 = ch, a1 = ch, a2 = ch, a3 = ch;
            a0 = __builtin_amdgcn_mfma_f32_16x16x32_f16(cf0, p0a, a0, 0, 0, 0);
            a0 = __builtin_amdgcn_mfma_f32_16x16x32_f16(cf1, p0b, a0, 0, 0, 0);
            a1 = __builtin_amdgcn_mfma_f32_16x16x32_f16(cf0, p1a, a1, 0, 0, 0);
            a1 = __builtin_amdgcn_mfma_f32_16x16x32_f16(cf1, p1b, a1, 0, 0, 0);
            a2 = __builtin_amdgcn_mfma_f32_16x16x32_f16(cf0, p2a, a2, 0, 0, 0);
            a2 = __builtin_amdgcn_mfma_f32_16x16x32_f16(cf1, p2b, a2, 0, 0, 0);
            a3 = __builtin_amdgcn_mfma_f32_16x16x32_f16(cf0, p3a, a3, 0, 0, 0);
            a3 = __builtin_amdgcn_mfma_f32_16x16x32_f16(cf1, p3b, a3, 0, 0, 0);
            const int cbase = base + m * 16 + hi * 4;

            float mx;
            mx = vmax4(a0); m0 = fmaxf(m0, mx);
            if (mx >= m0 - MARGIN_S) {
                #pragma unroll
                for (int r = 0; r < 4; ++r) {
                    float sv = a0[r];
                    if (sv >= m0 - MARGIN_S)
                        rins(sv, cbase + r, n0, s00, s01, s02, s03, i00, i01, i02, i03);
                }
            }
            mx = vmax4(a1); m1 = fmaxf(m1, mx);
            if (mx >= m1 - MARGIN_S) {
                #pragma unroll
                for (int r = 0; r < 4; ++r) {
                    float sv = a1[r];
                    if (sv >= m1 - MARGIN_S)
                        rins(sv, cbase + r, n1, s10, s11, s12, s13, i10, i11, i12, i13);
                }
            }
            mx = vmax4(a2); m2 = fmaxf(m2, mx);
            if (mx >= m2 - MARGIN_S) {
                #pragma unroll
                for (int r = 0; r < 4; ++r) {
                    float sv = a2[r];
                    if (sv >= m2 - MARGIN_S)
                        rins(sv, cbase + r, n2, s20, s21, s22, s23, i20, i21, i22, i23);
                }
            }
            mx = vmax4(a3); m3 = fmaxf(m3, mx);
            if (mx >= m3 - MARGIN_S) {
                #pragma unroll
                for (int r = 0; r < 4; ++r) {
                    float sv = a3[r];
                    if (sv >= m3 - MARGIN_S)
                        rins(sv, cbase + r, n3, s30, s31, s32, s33, i30, i31, i32, i33);
                }
            }
        }
    }

    // global (per-point) max across the 4 hi-lanes -> final threshold
    m0 = fmaxf(m0, __shfl_xor(m0, 16)); m0 = fmaxf(m0, __shfl_xor(m0, 32));
    m1 = fmaxf(m1, __shfl_xor(m1, 16)); m1 = fmaxf(m1, __shfl_xor(m1, 32));
    m2 = fmaxf(m2, __shfl_xor(m2, 16)); m2 = fmaxf(m2, __shfl_xor(m2, 32));
    m3 = fmaxf(m3, __shfl_xor(m3, 16)); m3 = fmaxf(m3, __shfl_xor(m3, 32));

    // ======== exact fp32 resolve (round-1 arithmetic) ========
    float bd0, bd1, bd2, bd3;
    int   bi0, bi1, bi2, bi3;
    resolve_r(batch, cent, csq, pr0, hi, m0 - MARGIN_S, n0,
              s00, s01, s02, s03, i00, i01, i02, i03, bd0, bi0);
    resolve_r(batch, cent, csq, pr1, hi, m1 - MARGIN_S, n1,
              s10, s11, s12, s13, i10, i11, i12, i13, bd1, bi1);
    resolve_r(batch, cent, csq, pr2, hi, m2 - MARGIN_S, n2,
              s20, s21, s22, s23, i20, i21, i22, i23, bd2, bi2);
    resolve_r(batch, cent, csq, pr3, hi, m3 - MARGIN_S, n3,
              s30, s31, s32, s33, i30, i31, i32, i33, bd3, bi3);

    #pragma unroll
    for (int off = 16; off <= 32; off <<= 1) {
        float od; int oi;
        od = __shfl_xor(bd0, off); oi = __shfl_xor(bi0, off);
        if (od < bd0 || (od == bd0 && oi < bi0)) { bd0 = od; bi0 = oi; }
        od = __shfl_xor(bd1, off); oi = __shfl_xor(bi1, off);
        if (od < bd1 || (od == bd1 && oi < bi1)) { bd1 = od; bi1 = oi; }
        od = __shfl_xor(bd2, off); oi = __shfl_xor(bi2, off);
        if (od < bd2 || (od == bd2 && oi < bi2)) { bd2 = od; bi2 = oi; }
        od = __shfl_xor(bd3, off); oi = __shfl_xor(bi3, off);
        if (od < bd3 || (od == bd3 && oi < bi3)) { bd3 = od; bi3 = oi; }
    }

    if (hi == 0) {
        out_assign[pr0] = (float)bi0;
        out_assign[pr1] = (float)bi1;
        out_assign[pr2] = (float)bi2;
        out_assign[pr3] = (float)bi3;
    }

    // =================== fused scatter (fire-and-forget atomics) ================
    const int split = (blockIdx.x * WAVES_PER_BLK + wave) & split_mask;
    float* ps = ps_base + (size_t)split * K_CL * D;
    float* cs = cs_base + (size_t)split * K_CL;
    #pragma unroll 4
    for (int s = 0; s < 4; ++s) {
        int bis = (s == 0) ? bi0 : (s == 1) ? bi1 : (s == 2) ? bi2 : bi3;
        for (int p = 0; p < 16; ++p) {
            int a = __shfl(bis, p);                      // cluster of point (s,p)
            int pt = wbase + s * 16 + p;
            float v = batch[(size_t)pt * D + lane];      // lane = dim, coalesced
            atomicAdd(&ps[(size_t)a * D + lane], v);
            if (lane == 0) atomicAdd(&cs[a], 1.0f);
        }
    }
}

__global__ __launch_bounds__(256) void reduce_kernel(
    const float* __restrict__ partial,
    const float* __restrict__ cnt_partial,
    float* __restrict__ out_counts,
    float* __restrict__ out_sums,
    int nsplit)
{
    int idx = blockIdx.x * 256 + threadIdx.x;
    if (idx < K_CL * D) {
        float s = 0.f;
        for (int e = 0; e < nsplit; ++e) s += partial[(size_t)e * K_CL * D + idx];
        out_sums[idx] = s;
    } else if (idx < K_CL * D + K_CL) {
        int c = idx - K_CL * D;
        float s = 0.f;
        for (int e = 0; e < nsplit; ++e) s += cnt_partial[e * K_CL + c];
        out_counts[c] = s;
    }
}

extern "C" void kernel_launch(void* const* d_in, const int* in_sizes, int n_in,
                              void* d_out, int out_size, void* d_ws, size_t ws_size,
                              hipStream_t stream) {
    const float* batch = (const float*)d_in[0];
    const float* cent  = (const float*)d_in[1];
    float* out        = (float*)d_out;
    float* out_assign = out;
    float* out_counts = out + N_PTS;
    float* out_sums   = out + N_PTS + K_CL;

    char* ws = (char*)d_ws;
    float* csq    = (float*)ws;                         // 4 KB
    float* csqhn  = (float*)(ws + 4096);                // 4 KB
    f16*   cent16 = (f16*)(ws + 8192);                  // 128 KB
    float* partial = (float*)(ws + 8192 + 131072);

    // pick largest nsplit that fits ws (32 -> 16 -> 8 -> 4 -> 2 -> direct)
    int nsplit = 0;
    for (int ns = 32; ns >= 2; ns >>= 1) {
        size_t need = 8192 + 131072 +
                      (size_t)ns * K_CL * D * 4 + (size_t)ns * K_CL * 4;
        if (ws_size >= need) { nsplit = ns; break; }
    }

    prep_kernel<<<K_CL / 256, 256, 0, stream>>>(cent, csq, csqhn, cent16);

    if (nsplit > 0) {
        float* cnt_partial = partial + (size_t)nsplit * K_CL * D;
        (void)hipMemsetAsync(partial, 0,
                       (size_t)(nsplit * K_CL * D + nsplit * K_CL) * sizeof(float), stream);
        assign_kernel<<<N_PTS / PTS_PER_BLK, 1024, 0, stream>>>(
            batch, cent16, csq, csqhn, cent, out_assign,
            partial, cnt_partial, nsplit - 1);
        reduce_kernel<<<(K_CL * D + K_CL + 255) / 256, 256, 0, stream>>>(
            partial, cnt_partial, out_counts, out_sums, nsplit);
    } else {
        (void)hipMemsetAsync(out_counts, 0, (size_t)(K_CL + K_CL * D) * sizeof(float), stream);
        assign_kernel<<<N_PTS / PTS_PER_BLK, 1024, 0, stream>>>(
            batch, cent16, csq, csqhn, cent, out_assign,
            out_sums, out_counts, 0);
    }
}

// Round 14
// 281.631 us; speedup vs baseline: 2.3397x; 2.3397x over previous
//
#include <hip/hip_runtime.h>
#include <float.h>

#define N_PTS 262144
#define K_CL  1024
#define D     64
#define PTS_PER_WAVE   64
#define WAVES_PER_BLK  16
#define PTS_PER_BLK    (PTS_PER_WAVE * WAVES_PER_BLK)   // 1024
#define NTILE 8
#define MARGIN_S 0.5f        // score margin (distance margin 1.0; fp16 err bound ~0.1)
#define CAND_CAP 6
#define SBLK 64              // scatter blocks (4096 pts each)
#define PPB  (N_PTS / SBLK)  // 4096

typedef _Float16 f16;
typedef _Float16 half8 __attribute__((ext_vector_type(8)));
typedef float    f32x4 __attribute__((ext_vector_type(4)));

// ---- prep: csq (exact fp32), csqhn = -0.5*csq, cent16 = fp16 PRE-SWIZZLED
__global__ __launch_bounds__(256) void prep_kernel(const float* __restrict__ cent,
                                                   float* __restrict__ csq,
                                                   float* __restrict__ csqhn,
                                                   f16* __restrict__ cent16) {
    int k = blockIdx.x * 256 + threadIdx.x;
    if (k >= K_CL) return;
    const float* row = &cent[(size_t)k * D];
    float s = 0.f;
    #pragma unroll
    for (int d = 0; d < D; ++d) s = fmaf(row[d], row[d], s);
    csq[k]   = s;
    csqhn[k] = -0.5f * s;
    int sw = k & 7;
    #pragma unroll
    for (int ch = 0; ch < 8; ++ch) {
        half8 h;
        #pragma unroll
        for (int e = 0; e < 8; ++e) h[e] = (f16)row[ch * 8 + e];
        *reinterpret_cast<half8*>(&cent16[(size_t)k * D + (size_t)((ch ^ sw) * 8)]) = h;
    }
}

__device__ __forceinline__ float exact_dist(const float* __restrict__ xr,
                                            const float* __restrict__ cr,
                                            float xsq, float cs) {
    float dot = 0.f;
    #pragma unroll
    for (int d = 0; d < D; ++d) dot = fmaf(xr[d], cr[d], dot);
    return (xsq - 2.0f * dot) + cs;
}

__device__ __forceinline__ half8 point_frag(const float* __restrict__ batch,
                                            int prow, int chunk) {
    const float* src = &batch[(size_t)prow * D + chunk * 8];
    float4 u0 = *reinterpret_cast<const float4*>(src);
    float4 u1 = *reinterpret_cast<const float4*>(src + 4);
    half8 h;
    h[0] = (f16)u0.x; h[1] = (f16)u0.y; h[2] = (f16)u0.z; h[3] = (f16)u0.w;
    h[4] = (f16)u1.x; h[5] = (f16)u1.y; h[6] = (f16)u1.z; h[7] = (f16)u1.w;
    return h;
}

__device__ __forceinline__ float vmax4(const f32x4& a) {
    return fmaxf(fmaxf(a.x, a.y), fmaxf(a.z, a.w));
}

__device__ __forceinline__ void collect(const f32x4& a, float thr, int cbase, int& cnt,
                                        int& s0, int& s1, int& s2, int& s3, int& s4, int& s5) {
    if (vmax4(a) >= thr) {
        #pragma unroll
        for (int r = 0; r < 4; ++r) {
            if (a[r] >= thr) {
                int c = cbase + r;
                if      (cnt == 0) s0 = c;
                else if (cnt == 1) s1 = c;
                else if (cnt == 2) s2 = c;
                else if (cnt == 3) s3 = c;
                else if (cnt == 4) s4 = c;
                else if (cnt == 5) s5 = c;
                cnt++;
            }
        }
    }
}

__device__ __forceinline__ void resolve(const float* __restrict__ batch,
                                        const float* __restrict__ cent,
                                        const float* __restrict__ csq,
                                        int prow, int hi, int cnt,
                                        int s0, int s1, int s2, int s3, int s4, int s5,
                                        float& bd, int& bi) {
    bd = FLT_MAX; bi = 0x7fffffff;
    if (cnt == 0) return;
    const float* xr = &batch[(size_t)prow * D];
    float xsq = 0.f;
    #pragma unroll
    for (int d = 0; d < D; ++d) xsq = fmaf(xr[d], xr[d], xsq);
    if (cnt <= CAND_CAP) {
        #pragma unroll
        for (int r = 0; r < CAND_CAP; ++r) {
            int c = (r == 0) ? s0 : (r == 1) ? s1 : (r == 2) ? s2
                  : (r == 3) ? s3 : (r == 4) ? s4 : s5;
            if (r < cnt) {
                float dd = exact_dist(xr, &cent[(size_t)c * D], xsq, csq[c]);
                if (dd < bd || (dd == bd && c < bi)) { bd = dd; bi = c; }
            }
        }
    } else {  // overflow (P ~ 0 with final-max threshold): exact scan of lane's slice
        for (int t16 = 0; t16 < 64; ++t16) {
            #pragma unroll
            for (int r = 0; r < 4; ++r) {
                int c = t16 * 16 + hi * 4 + r;
                float dd = exact_dist(xr, &cent[(size_t)c * D], xsq, csq[c]);
                if (dd < bd || (dd == bd && c < bi)) { bd = dd; bi = c; }
            }
        }
    }
}

// 1024 threads, 16 waves, 1 block/CU; full centroid set in LDS, single barrier.
// (round-10 standalone form, measured 99 us / MfmaUtil 29%)
__global__ __launch_bounds__(1024, 4) void assign_kernel(
    const float* __restrict__ batch,
    const f16*   __restrict__ cent16,
    const float* __restrict__ csq,
    const float* __restrict__ csqhn,
    const float* __restrict__ cent,
    float* __restrict__ out_assign)
{
    __shared__ f16   C16[K_CL * D];              // 128 KB, swizzled phys layout
    __shared__ __align__(16) float CH[K_CL];     // 4 KB (-0.5*csq)

    const int tid   = threadIdx.x;
    const int wave  = tid >> 6;
    const int lane  = tid & 63;
    const int lo    = lane & 15;
    const int hi    = lane >> 4;
    const int wbase = (blockIdx.x * WAVES_PER_BLK + wave) * PTS_PER_WAVE;

    #pragma unroll
    for (int it = 0; it < 8; ++it) {
        int u = tid + 1024 * it;
        *reinterpret_cast<half8*>(&C16[u * 8]) =
            *reinterpret_cast<const half8*>(&cent16[(size_t)u * 8]);
    }
    CH[tid] = csqhn[tid];
    __syncthreads();

    const int pr0 = wbase + 0 * 16 + lo;
    const int pr1 = wbase + 1 * 16 + lo;
    const int pr2 = wbase + 2 * 16 + lo;
    const int pr3 = wbase + 3 * 16 + lo;

    const half8 p0a = point_frag(batch, pr0, hi), p0b = point_frag(batch, pr0, 4 + hi);
    const half8 p1a = point_frag(batch, pr1, hi), p1b = point_frag(batch, pr1, 4 + hi);
    const half8 p2a = point_frag(batch, pr2, hi), p2b = point_frag(batch, pr2, 4 + hi);
    const half8 p3a = point_frag(batch, pr3, hi), p3b = point_frag(batch, pr3, 4 + hi);

    // =================== PASS 1: branch-free final max (LDS operands) ===========
    float m0 = -FLT_MAX, m1 = -FLT_MAX, m2 = -FLT_MAX, m3 = -FLT_MAX;
    for (int t = 0; t < NTILE; ++t) {
        const int base = t * 128;
        #pragma unroll
        for (int m = 0; m < 8; ++m) {
            const int row = base + m * 16 + lo;
            const int sw  = row & 7;
            const half8 cf0 = *reinterpret_cast<const half8*>(&C16[row * D + ((hi     ^ sw) * 8)]);
            const half8 cf1 = *reinterpret_cast<const half8*>(&C16[row * D + (((4+hi) ^ sw) * 8)]);
            const f32x4 ch  = *reinterpret_cast<const f32x4*>(&CH[base + m * 16 + hi * 4]);
            f32x4 a0 = ch, a1 = ch, a2 = ch, a3 = ch;
            a0 = __builtin_amdgcn_mfma_f32_16x16x32_f16(cf0, p0a, a0, 0, 0, 0);
            a0 = __builtin_amdgcn_mfma_f32_16x16x32_f16(cf1, p0b, a0, 0, 0, 0);
            a1 = __builtin_amdgcn_mfma_f32_16x16x32_f16(cf0, p1a, a1, 0, 0, 0);
            a1 = __builtin_amdgcn_mfma_f32_16x16x32_f16(cf1, p1b, a1, 0, 0, 0);
            a2 = __builtin_amdgcn_mfma_f32_16x16x32_f16(cf0, p2a, a2, 0, 0, 0);
            a2 = __builtin_amdgcn_mfma_f32_16x16x32_f16(cf1, p2b, a2, 0, 0, 0);
            a3 = __builtin_amdgcn_mfma_f32_16x16x32_f16(cf0, p3a, a3, 0, 0, 0);
            a3 = __builtin_amdgcn_mfma_f32_16x16x32_f16(cf1, p3b, a3, 0, 0, 0);
            m0 = fmaxf(m0, vmax4(a0));
            m1 = fmaxf(m1, vmax4(a1));
            m2 = fmaxf(m2, vmax4(a2));
            m3 = fmaxf(m3, vmax4(a3));
        }
    }
    m0 = fmaxf(m0, __shfl_xor(m0, 16)); m0 = fmaxf(m0, __shfl_xor(m0, 32));
    m1 = fmaxf(m1, __shfl_xor(m1, 16)); m1 = fmaxf(m1, __shfl_xor(m1, 32));
    m2 = fmaxf(m2, __shfl_xor(m2, 16)); m2 = fmaxf(m2, __shfl_xor(m2, 32));
    m3 = fmaxf(m3, __shfl_xor(m3, 16)); m3 = fmaxf(m3, __shfl_xor(m3, 32));
    const float t0 = m0 - MARGIN_S, t1 = m1 - MARGIN_S,
                t2 = m2 - MARGIN_S, t3 = m3 - MARGIN_S;

    // =================== PASS 2: collect candidates vs final threshold ==========
    int n0 = 0, n1 = 0, n2 = 0, n3 = 0;
    int a0c0=0,a0c1=0,a0c2=0,a0c3=0,a0c4=0,a0c5=0;
    int a1c0=0,a1c1=0,a1c2=0,a1c3=0,a1c4=0,a1c5=0;
    int a2c0=0,a2c1=0,a2c2=0,a2c3=0,a2c4=0,a2c5=0;
    int a3c0=0,a3c1=0,a3c2=0,a3c3=0,a3c4=0,a3c5=0;

    for (int t = 0; t < NTILE; ++t) {
        const int base = t * 128;
        #pragma unroll
        for (int m = 0; m < 8; ++m) {
            const int row = base + m * 16 + lo;
            const int sw  = row & 7;
            const half8 cf0 = *reinterpret_cast<const half8*>(&C16[row * D + ((hi     ^ sw) * 8)]);
            const half8 cf1 = *reinterpret_cast<const half8*>(&C16[row * D + (((4+hi) ^ sw) * 8)]);
            const f32x4 ch  = *reinterpret_cast<const f32x4*>(&CH[base + m * 16 + hi * 4]);
            f32x4 a0 = ch, a1 = ch, a2 = ch, a3 = ch;
            a0 = __builtin_amdgcn_mfma_f32_16x16x32_f16(cf0, p0a, a0, 0, 0, 0);
            a0 = __builtin_amdgcn_mfma_f32_16x16x32_f16(cf1, p0b, a0, 0, 0, 0);
            a1 = __builtin_amdgcn_mfma_f32_16x16x32_f16(cf0, p1a, a1, 0, 0, 0);
            a1 = __builtin_amdgcn_mfma_f32_16x16x32_f16(cf1, p1b, a1, 0, 0, 0);
            a2 = __builtin_amdgcn_mfma_f32_16x16x32_f16(cf0, p2a, a2, 0, 0, 0);
            a2 = __builtin_amdgcn_mfma_f32_16x16x32_f16(cf1, p2b, a2, 0, 0, 0);
            a3 = __builtin_amdgcn_mfma_f32_16x16x32_f16(cf0, p3a, a3, 0, 0, 0);
            a3 = __builtin_amdgcn_mfma_f32_16x16x32_f16(cf1, p3b, a3, 0, 0, 0);
            const int cbase = base + m * 16 + hi * 4;
            collect(a0, t0, cbase, n0, a0c0, a0c1, a0c2, a0c3, a0c4, a0c5);
            collect(a1, t1, cbase, n1, a1c0, a1c1, a1c2, a1c3, a1c4, a1c5);
            collect(a2, t2, cbase, n2, a2c0, a2c1, a2c2, a2c3, a2c4, a2c5);
            collect(a3, t3, cbase, n3, a3c0, a3c1, a3c2, a3c3, a3c4, a3c5);
        }
    }

    // =================== exact fp32 resolve (round-1 arithmetic) ================
    float bd0, bd1, bd2, bd3;
    int   bi0, bi1, bi2, bi3;
    resolve(batch, cent, csq, pr0, hi, n0, a0c0, a0c1, a0c2, a0c3, a0c4, a0c5, bd0, bi0);
    resolve(batch, cent, csq, pr1, hi, n1, a1c0, a1c1, a1c2, a1c3, a1c4, a1c5, bd1, bi1);
    resolve(batch, cent, csq, pr2, hi, n2, a2c0, a2c1, a2c2, a2c3, a2c4, a2c5, bd2, bi2);
    resolve(batch, cent, csq, pr3, hi, n3, a3c0, a3c1, a3c2, a3c3, a3c4, a3c5, bd3, bi3);

    #pragma unroll
    for (int off = 16; off <= 32; off <<= 1) {
        float od; int oi;
        od = __shfl_xor(bd0, off); oi = __shfl_xor(bi0, off);
        if (od < bd0 || (od == bd0 && oi < bi0)) { bd0 = od; bi0 = oi; }
        od = __shfl_xor(bd1, off); oi = __shfl_xor(bi1, off);
        if (od < bd1 || (od == bd1 && oi < bi1)) { bd1 = od; bi1 = oi; }
        od = __shfl_xor(bd2, off); oi = __shfl_xor(bi2, off);
        if (od < bd2 || (od == bd2 && oi < bi2)) { bd2 = od; bi2 = oi; }
        od = __shfl_xor(bd3, off); oi = __shfl_xor(bi3, off);
        if (od < bd3 || (od == bd3 && oi < bi3)) { bd3 = od; bi3 = oi; }
    }

    if (hi == 0) {
        out_assign[pr0] = (float)bi0;
        out_assign[pr1] = (float)bi1;
        out_assign[pr2] = (float)bi2;
        out_assign[pr3] = (float)bi3;
    }
}

// ---- LDS-compressed scatter: 64 blocks x 4096 points. Wave w owns clusters
// [64w, 64w+64): exclusive f16 LDS partition (no atomics in accumulation),
// then one f32 atomic row per (cluster, block): 4.2M atomics (4x fewer than fused).
__global__ __launch_bounds__(1024) void scatter_lds_kernel(
    const float* __restrict__ batch,
    const float* __restrict__ assignF,
    float* __restrict__ out_counts,
    float* __restrict__ out_sums)
{
    __shared__ f16 S16[K_CL * D];      // 128 KB f16 sums
    __shared__ int acnt[K_CL];         // 4 KB counts
    __shared__ int a_lds[PPB];         // 16 KB assignments

    const int tid  = threadIdx.x;
    const int wave = tid >> 6;
    const int lane = tid & 63;
    const size_t pbase = (size_t)blockIdx.x * PPB;

    #pragma unroll
    for (int i = 0; i < 8; ++i) {
        int4 z = {0, 0, 0, 0};
        *reinterpret_cast<int4*>(&S16[(tid + 1024 * i) * 8]) = z;
    }
    if (tid < K_CL) acnt[tid] = 0;
    #pragma unroll
    for (int i = 0; i < 4; ++i) {
        int pl = tid + 1024 * i;
        a_lds[pl] = (int)assignF[pbase + pl];
    }
    __syncthreads();

    // accumulate: scan all points, claim those in this wave's cluster range
    for (int chunk = 0; chunk < PPB / 64; ++chunk) {
        int a_l = a_lds[chunk * 64 + lane];
        unsigned long long mask = __ballot((a_l >> 6) == wave);
        while (mask) {
            int bit = __builtin_ctzll(mask);
            mask &= mask - 1;
            int pp = chunk * 64 + bit;
            int c  = __shfl(a_l, bit);
            float v = batch[(pbase + pp) * D + lane];        // 256B coalesced row
            S16[c * D + lane] = (f16)((float)S16[c * D + lane] + v);
            if (lane == 0) acnt[c]++;
        }
    }
    __syncthreads();

    // flush this wave's 64 clusters
    const int c0 = wave * 64;
    for (int i = 0; i < 64; ++i) {
        int c = c0 + i;
        int n = acnt[c];
        if (n > 0) {
            atomicAdd(&out_sums[(size_t)c * D + lane], (float)S16[c * D + lane]);
            if (lane == 0) atomicAdd(&out_counts[c], (float)n);
        }
    }
}

// ---- fallback if ws too small for prep outputs: brute-force fp32 (never expected)
__global__ __launch_bounds__(256) void assign_bruteforce_kernel(
    const float* __restrict__ batch,
    const float* __restrict__ cent,
    float* __restrict__ out_assign)
{
    const int p = blockIdx.x * 256 + threadIdx.x;
    if (p >= N_PTS) return;
    const float* xr = &batch[(size_t)p * D];
    float xsq = 0.f;
    #pragma unroll
    for (int d = 0; d < D; ++d) xsq = fmaf(xr[d], xr[d], xsq);
    float bd = FLT_MAX; int bi = 0;
    for (int c = 0; c < K_CL; ++c) {
        const float* cr = &cent[(size_t)c * D];
        float dot = 0.f, cs = 0.f;
        #pragma unroll
        for (int d = 0; d < D; ++d) { dot = fmaf(xr[d], cr[d], dot); cs = fmaf(cr[d], cr[d], cs); }
        float dd = (xsq - 2.0f * dot) + cs;
        if (dd < bd) { bd = dd; bi = c; }
    }
    out_assign[p] = (float)bi;
}

extern "C" void kernel_launch(void* const* d_in, const int* in_sizes, int n_in,
                              void* d_out, int out_size, void* d_ws, size_t ws_size,
                              hipStream_t stream) {
    const float* batch = (const float*)d_in[0];
    const float* cent  = (const float*)d_in[1];
    float* out        = (float*)d_out;
    float* out_assign = out;
    float* out_counts = out + N_PTS;
    float* out_sums   = out + N_PTS + K_CL;

    char* ws = (char*)d_ws;
    float* csq    = (float*)ws;                         // 4 KB
    float* csqhn  = (float*)(ws + 4096);                // 4 KB
    f16*   cent16 = (f16*)(ws + 8192);                  // 128 KB
    const size_t need = 8192 + 131072;

    (void)hipMemsetAsync(out_counts, 0, (size_t)(K_CL + K_CL * D) * sizeof(float), stream);

    if (ws_size >= need) {
        prep_kernel<<<K_CL / 256, 256, 0, stream>>>(cent, csq, csqhn, cent16);
        assign_kernel<<<N_PTS / PTS_PER_BLK, 1024, 0, stream>>>(
            batch, cent16, csq, csqhn, cent, out_assign);
    } else {
        assign_bruteforce_kernel<<<N_PTS / 256, 256, 0, stream>>>(batch, cent, out_assign);
    }
    scatter_lds_kernel<<<SBLK, 1024, 0, stream>>>(batch, out_assign, out_counts, out_sums);
}

// Round 15
// 215.151 us; speedup vs baseline: 3.0627x; 1.3090x over previous
//
#include <hip/hip_runtime.h>
#include <float.h>

#define N_PTS 262144
#define K_CL  1024
#define D     64
#define PTS_PER_WAVE   64
#define WAVES_PER_BLK  16
#define PTS_PER_BLK    (PTS_PER_WAVE * WAVES_PER_BLK)   // 1024
#define NBLK (N_PTS / PTS_PER_BLK)                      // 256
#define NTILE 8
#define MARGIN_S 0.5f        // score margin (distance margin 1.0; fp16 err bound ~0.1)
#define CAND_CAP 6
#define HKC (K_CL / 2)       // 512 clusters per half-pass

typedef _Float16 f16;
typedef _Float16 half8 __attribute__((ext_vector_type(8)));
typedef float    f32x4 __attribute__((ext_vector_type(4)));

// ---- prep: csq (exact fp32), csqhn = -0.5*csq, cent16 = fp16 PRE-SWIZZLED
__global__ __launch_bounds__(256) void prep_kernel(const float* __restrict__ cent,
                                                   float* __restrict__ csq,
                                                   float* __restrict__ csqhn,
                                                   f16* __restrict__ cent16) {
    int k = blockIdx.x * 256 + threadIdx.x;
    if (k >= K_CL) return;
    const float* row = &cent[(size_t)k * D];
    float s = 0.f;
    #pragma unroll
    for (int d = 0; d < D; ++d) s = fmaf(row[d], row[d], s);
    csq[k]   = s;
    csqhn[k] = -0.5f * s;
    int sw = k & 7;
    #pragma unroll
    for (int ch = 0; ch < 8; ++ch) {
        half8 h;
        #pragma unroll
        for (int e = 0; e < 8; ++e) h[e] = (f16)row[ch * 8 + e];
        *reinterpret_cast<half8*>(&cent16[(size_t)k * D + (size_t)((ch ^ sw) * 8)]) = h;
    }
}

__device__ __forceinline__ float exact_dist(const float* __restrict__ xr,
                                            const float* __restrict__ cr,
                                            float xsq, float cs) {
    float dot = 0.f;
    #pragma unroll
    for (int d = 0; d < D; ++d) dot = fmaf(xr[d], cr[d], dot);
    return (xsq - 2.0f * dot) + cs;
}

__device__ __forceinline__ half8 point_frag(const float* __restrict__ batch,
                                            int prow, int chunk) {
    const float* src = &batch[(size_t)prow * D + chunk * 8];
    float4 u0 = *reinterpret_cast<const float4*>(src);
    float4 u1 = *reinterpret_cast<const float4*>(src + 4);
    half8 h;
    h[0] = (f16)u0.x; h[1] = (f16)u0.y; h[2] = (f16)u0.z; h[3] = (f16)u0.w;
    h[4] = (f16)u1.x; h[5] = (f16)u1.y; h[6] = (f16)u1.z; h[7] = (f16)u1.w;
    return h;
}

__device__ __forceinline__ float vmax4(const f32x4& a) {
    return fmaxf(fmaxf(a.x, a.y), fmaxf(a.z, a.w));
}

__device__ __forceinline__ void collect(const f32x4& a, float thr, int cbase, int& cnt,
                                        int& s0, int& s1, int& s2, int& s3, int& s4, int& s5) {
    if (vmax4(a) >= thr) {
        #pragma unroll
        for (int r = 0; r < 4; ++r) {
            if (a[r] >= thr) {
                int c = cbase + r;
                if      (cnt == 0) s0 = c;
                else if (cnt == 1) s1 = c;
                else if (cnt == 2) s2 = c;
                else if (cnt == 3) s3 = c;
                else if (cnt == 4) s4 = c;
                else if (cnt == 5) s5 = c;
                cnt++;
            }
        }
    }
}

__device__ __forceinline__ void resolve(const float* __restrict__ batch,
                                        const float* __restrict__ cent,
                                        const float* __restrict__ csq,
                                        int prow, int hi, int cnt,
                                        int s0, int s1, int s2, int s3, int s4, int s5,
                                        float& bd, int& bi) {
    bd = FLT_MAX; bi = 0x7fffffff;
    if (cnt == 0) return;
    const float* xr = &batch[(size_t)prow * D];
    float xsq = 0.f;
    #pragma unroll
    for (int d = 0; d < D; ++d) xsq = fmaf(xr[d], xr[d], xsq);
    if (cnt <= CAND_CAP) {
        #pragma unroll
        for (int r = 0; r < CAND_CAP; ++r) {
            int c = (r == 0) ? s0 : (r == 1) ? s1 : (r == 2) ? s2
                  : (r == 3) ? s3 : (r == 4) ? s4 : s5;
            if (r < cnt) {
                float dd = exact_dist(xr, &cent[(size_t)c * D], xsq, csq[c]);
                if (dd < bd || (dd == bd && c < bi)) { bd = dd; bi = c; }
            }
        }
    } else {  // overflow (P ~ 0 with final-max threshold): exact scan of lane's slice
        for (int t16 = 0; t16 < 64; ++t16) {
            #pragma unroll
            for (int r = 0; r < 4; ++r) {
                int c = t16 * 16 + hi * 4 + r;
                float dd = exact_dist(xr, &cent[(size_t)c * D], xsq, csq[c]);
                if (dd < bd || (dd == bd && c < bi)) { bd = dd; bi = c; }
            }
        }
    }
}

// TAIL: 0 = global-atomic nsplit partials (round-11 proven), 1 = f16 store-all
// partials, 2 = f32 store-all partials. Compute phase identical in all.
template<int TAIL>
__global__ __launch_bounds__(1024, 4) void assign_kernel(
    const float* __restrict__ batch,
    const f16*   __restrict__ cent16,
    const float* __restrict__ csq,
    const float* __restrict__ csqhn,
    const float* __restrict__ cent,
    float* __restrict__ out_assign,
    void*  __restrict__ part,        // TAIL0: f32 [nsplit][K][D]; TAIL1: f16 [256][K*D]; TAIL2: f32 [256][K*D]
    float* __restrict__ cs_base,     // TAIL0: [nsplit][K]; TAIL1/2: [256][K]
    int split_mask)
{
    __shared__ __align__(16) f16   C16[K_CL * D];   // 128 KB, swizzled phys layout
    __shared__ __align__(16) float CH[K_CL];        // 4 KB (-0.5*csq); reused as a_sh
    __shared__ int acnt[K_CL];                      // 4 KB counts (TAIL>=1)

    const int tid   = threadIdx.x;
    const int wave  = tid >> 6;
    const int lane  = tid & 63;
    const int lo    = lane & 15;
    const int hi    = lane >> 4;
    const int wbase = (blockIdx.x * WAVES_PER_BLK + wave) * PTS_PER_WAVE;

    #pragma unroll
    for (int it = 0; it < 8; ++it) {
        int u = tid + 1024 * it;
        *reinterpret_cast<half8*>(&C16[u * 8]) =
            *reinterpret_cast<const half8*>(&cent16[(size_t)u * 8]);
    }
    CH[tid] = csqhn[tid];
    __syncthreads();

    const int pr0 = wbase + 0 * 16 + lo;
    const int pr1 = wbase + 1 * 16 + lo;
    const int pr2 = wbase + 2 * 16 + lo;
    const int pr3 = wbase + 3 * 16 + lo;

    const half8 p0a = point_frag(batch, pr0, hi), p0b = point_frag(batch, pr0, 4 + hi);
    const half8 p1a = point_frag(batch, pr1, hi), p1b = point_frag(batch, pr1, 4 + hi);
    const half8 p2a = point_frag(batch, pr2, hi), p2b = point_frag(batch, pr2, 4 + hi);
    const half8 p3a = point_frag(batch, pr3, hi), p3b = point_frag(batch, pr3, 4 + hi);

    // =================== PASS 1: branch-free final max (LDS operands) ===========
    float m0 = -FLT_MAX, m1 = -FLT_MAX, m2 = -FLT_MAX, m3 = -FLT_MAX;
    for (int t = 0; t < NTILE; ++t) {
        const int base = t * 128;
        #pragma unroll
        for (int m = 0; m < 8; ++m) {
            const int row = base + m * 16 + lo;
            const int sw  = row & 7;
            const half8 cf0 = *reinterpret_cast<const half8*>(&C16[row * D + ((hi     ^ sw) * 8)]);
            const half8 cf1 = *reinterpret_cast<const half8*>(&C16[row * D + (((4+hi) ^ sw) * 8)]);
            const f32x4 ch  = *reinterpret_cast<const f32x4*>(&CH[base + m * 16 + hi * 4]);
            f32x4 a0 = ch, a1 = ch, a2 = ch, a3 = ch;
            a0 = __builtin_amdgcn_mfma_f32_16x16x32_f16(cf0, p0a, a0, 0, 0, 0);
            a0 = __builtin_amdgcn_mfma_f32_16x16x32_f16(cf1, p0b, a0, 0, 0, 0);
            a1 = __builtin_amdgcn_mfma_f32_16x16x32_f16(cf0, p1a, a1, 0, 0, 0);
            a1 = __builtin_amdgcn_mfma_f32_16x16x32_f16(cf1, p1b, a1, 0, 0, 0);
            a2 = __builtin_amdgcn_mfma_f32_16x16x32_f16(cf0, p2a, a2, 0, 0, 0);
            a2 = __builtin_amdgcn_mfma_f32_16x16x32_f16(cf1, p2b, a2, 0, 0, 0);
            a3 = __builtin_amdgcn_mfma_f32_16x16x32_f16(cf0, p3a, a3, 0, 0, 0);
            a3 = __builtin_amdgcn_mfma_f32_16x16x32_f16(cf1, p3b, a3, 0, 0, 0);
            m0 = fmaxf(m0, vmax4(a0));
            m1 = fmaxf(m1, vmax4(a1));
            m2 = fmaxf(m2, vmax4(a2));
            m3 = fmaxf(m3, vmax4(a3));
        }
    }
    m0 = fmaxf(m0, __shfl_xor(m0, 16)); m0 = fmaxf(m0, __shfl_xor(m0, 32));
    m1 = fmaxf(m1, __shfl_xor(m1, 16)); m1 = fmaxf(m1, __shfl_xor(m1, 32));
    m2 = fmaxf(m2, __shfl_xor(m2, 16)); m2 = fmaxf(m2, __shfl_xor(m2, 32));
    m3 = fmaxf(m3, __shfl_xor(m3, 16)); m3 = fmaxf(m3, __shfl_xor(m3, 32));
    const float t0 = m0 - MARGIN_S, t1 = m1 - MARGIN_S,
                t2 = m2 - MARGIN_S, t3 = m3 - MARGIN_S;

    // =================== PASS 2: collect candidates vs final threshold ==========
    int n0 = 0, n1 = 0, n2 = 0, n3 = 0;
    int a0c0=0,a0c1=0,a0c2=0,a0c3=0,a0c4=0,a0c5=0;
    int a1c0=0,a1c1=0,a1c2=0,a1c3=0,a1c4=0,a1c5=0;
    int a2c0=0,a2c1=0,a2c2=0,a2c3=0,a2c4=0,a2c5=0;
    int a3c0=0,a3c1=0,a3c2=0,a3c3=0,a3c4=0,a3c5=0;

    for (int t = 0; t < NTILE; ++t) {
        const int base = t * 128;
        #pragma unroll
        for (int m = 0; m < 8; ++m) {
            const int row = base + m * 16 + lo;
            const int sw  = row & 7;
            const half8 cf0 = *reinterpret_cast<const half8*>(&C16[row * D + ((hi     ^ sw) * 8)]);
            const half8 cf1 = *reinterpret_cast<const half8*>(&C16[row * D + (((4+hi) ^ sw) * 8)]);
            const f32x4 ch  = *reinterpret_cast<const f32x4*>(&CH[base + m * 16 + hi * 4]);
            f32x4 a0 = ch, a1 = ch, a2 = ch, a3 = ch;
            a0 = __builtin_amdgcn_mfma_f32_16x16x32_f16(cf0, p0a, a0, 0, 0, 0);
            a0 = __builtin_amdgcn_mfma_f32_16x16x32_f16(cf1, p0b, a0, 0, 0, 0);
            a1 = __builtin_amdgcn_mfma_f32_16x16x32_f16(cf0, p1a, a1, 0, 0, 0);
            a1 = __builtin_amdgcn_mfma_f32_16x16x32_f16(cf1, p1b, a1, 0, 0, 0);
            a2 = __builtin_amdgcn_mfma_f32_16x16x32_f16(cf0, p2a, a2, 0, 0, 0);
            a2 = __builtin_amdgcn_mfma_f32_16x16x32_f16(cf1, p2b, a2, 0, 0, 0);
            a3 = __builtin_amdgcn_mfma_f32_16x16x32_f16(cf0, p3a, a3, 0, 0, 0);
            a3 = __builtin_amdgcn_mfma_f32_16x16x32_f16(cf1, p3b, a3, 0, 0, 0);
            const int cbase = base + m * 16 + hi * 4;
            collect(a0, t0, cbase, n0, a0c0, a0c1, a0c2, a0c3, a0c4, a0c5);
            collect(a1, t1, cbase, n1, a1c0, a1c1, a1c2, a1c3, a1c4, a1c5);
            collect(a2, t2, cbase, n2, a2c0, a2c1, a2c2, a2c3, a2c4, a2c5);
            collect(a3, t3, cbase, n3, a3c0, a3c1, a3c2, a3c3, a3c4, a3c5);
        }
    }

    // =================== exact fp32 resolve (round-1 arithmetic) ================
    float bd0, bd1, bd2, bd3;
    int   bi0, bi1, bi2, bi3;
    resolve(batch, cent, csq, pr0, hi, n0, a0c0, a0c1, a0c2, a0c3, a0c4, a0c5, bd0, bi0);
    resolve(batch, cent, csq, pr1, hi, n1, a1c0, a1c1, a1c2, a1c3, a1c4, a1c5, bd1, bi1);
    resolve(batch, cent, csq, pr2, hi, n2, a2c0, a2c1, a2c2, a2c3, a2c4, a2c5, bd2, bi2);
    resolve(batch, cent, csq, pr3, hi, n3, a3c0, a3c1, a3c2, a3c3, a3c4, a3c5, bd3, bi3);

    #pragma unroll
    for (int off = 16; off <= 32; off <<= 1) {
        float od; int oi;
        od = __shfl_xor(bd0, off); oi = __shfl_xor(bi0, off);
        if (od < bd0 || (od == bd0 && oi < bi0)) { bd0 = od; bi0 = oi; }
        od = __shfl_xor(bd1, off); oi = __shfl_xor(bi1, off);
        if (od < bd1 || (od == bd1 && oi < bi1)) { bd1 = od; bi1 = oi; }
        od = __shfl_xor(bd2, off); oi = __shfl_xor(bi2, off);
        if (od < bd2 || (od == bd2 && oi < bi2)) { bd2 = od; bi2 = oi; }
        od = __shfl_xor(bd3, off); oi = __shfl_xor(bi3, off);
        if (od < bd3 || (od == bd3 && oi < bi3)) { bd3 = od; bi3 = oi; }
    }

    if (hi == 0) {
        out_assign[pr0] = (float)bi0;
        out_assign[pr1] = (float)bi1;
        out_assign[pr2] = (float)bi2;
        out_assign[pr3] = (float)bi3;
    }

    if constexpr (TAIL == 0) {
        // fused scatter: f32 fire-and-forget atomics into nsplit partials (66us proven)
        float* ps = (float*)part + (size_t)((blockIdx.x * WAVES_PER_BLK + wave) & split_mask) * K_CL * D;
        float* cs = cs_base + (size_t)((blockIdx.x * WAVES_PER_BLK + wave) & split_mask) * K_CL;
        #pragma unroll 4
        for (int s = 0; s < 4; ++s) {
            int bis = (s == 0) ? bi0 : (s == 1) ? bi1 : (s == 2) ? bi2 : bi3;
            for (int p = 0; p < 16; ++p) {
                int a = __shfl(bis, p);
                int pt = wbase + s * 16 + p;
                float v = batch[(size_t)pt * D + lane];
                atomicAdd(&ps[(size_t)a * D + lane], v);
                if (lane == 0) atomicAdd(&cs[a], 1.0f);
            }
        }
    } else {
        // ===== LDS-table tail: reuse C16 as f32 T[512][64]; CH as a_sh[1024] =====
        __syncthreads();                       // all waves done reading C16/CH
        float* T    = reinterpret_cast<float*>(C16);
        int*   a_sh = reinterpret_cast<int*>(CH);
        float4* T4  = reinterpret_cast<float4*>(T);
        {
            float4 z = {0.f, 0.f, 0.f, 0.f};
            #pragma unroll
            for (int i = 0; i < 8; ++i) T4[tid + 1024 * i] = z;
        }
        acnt[tid] = 0;
        if (hi == 0) {
            a_sh[wave * 64 + 0 * 16 + lo] = bi0;
            a_sh[wave * 64 + 1 * 16 + lo] = bi1;
            a_sh[wave * 64 + 2 * 16 + lo] = bi2;
            a_sh[wave * 64 + 3 * 16 + lo] = bi3;
        }
        __syncthreads();

        // pass A: clusters [0, 512) + counts; row loads independent -> pipelined
        #pragma unroll 4
        for (int p = 0; p < 64; ++p) {
            int a = a_sh[wave * 64 + p];
            if (lane == 0) atomicAdd(&acnt[a], 1);
            if (a < HKC) {
                float v = batch[(size_t)(wbase + p) * D + lane];
                atomicAdd(&T[a * D + lane], v);
            }
        }
        __syncthreads();

        const size_t pb = (size_t)blockIdx.x * (K_CL * D);
        if constexpr (TAIL == 2) {
            float4* dst = reinterpret_cast<float4*>((float*)part + pb);
            #pragma unroll
            for (int i = 0; i < 8; ++i) dst[tid + 1024 * i] = T4[tid + 1024 * i];
        } else {
            half8* dst = reinterpret_cast<half8*>((f16*)part + pb);
            #pragma unroll
            for (int i = 0; i < 4; ++i) {
                int u = tid + 1024 * i;
                float4 x0 = T4[u * 2], x1 = T4[u * 2 + 1];
                half8 h;
                h[0] = (f16)x0.x; h[1] = (f16)x0.y; h[2] = (f16)x0.z; h[3] = (f16)x0.w;
                h[4] = (f16)x1.x; h[5] = (f16)x1.y; h[6] = (f16)x1.z; h[7] = (f16)x1.w;
                dst[u] = h;
            }
        }
        cs_base[(size_t)blockIdx.x * K_CL + tid] = (float)acnt[tid];
        __syncthreads();

        {
            float4 z = {0.f, 0.f, 0.f, 0.f};
            #pragma unroll
            for (int i = 0; i < 8; ++i) T4[tid + 1024 * i] = z;
        }
        __syncthreads();

        // pass B: clusters [512, 1024)
        #pragma unroll 4
        for (int p = 0; p < 64; ++p) {
            int a = a_sh[wave * 64 + p];
            if (a >= HKC) {
                float v = batch[(size_t)(wbase + p) * D + lane];
                atomicAdd(&T[(a - HKC) * D + lane], v);
            }
        }
        __syncthreads();

        if constexpr (TAIL == 2) {
            float4* dst = reinterpret_cast<float4*>((float*)part + pb + (size_t)HKC * D);
            #pragma unroll
            for (int i = 0; i < 8; ++i) dst[tid + 1024 * i] = T4[tid + 1024 * i];
        } else {
            half8* dst = reinterpret_cast<half8*>((f16*)part + pb + (size_t)HKC * D);
            #pragma unroll
            for (int i = 0; i < 4; ++i) {
                int u = tid + 1024 * i;
                float4 x0 = T4[u * 2], x1 = T4[u * 2 + 1];
                half8 h;
                h[0] = (f16)x0.x; h[1] = (f16)x0.y; h[2] = (f16)x0.z; h[3] = (f16)x0.w;
                h[4] = (f16)x1.x; h[5] = (f16)x1.y; h[6] = (f16)x1.z; h[7] = (f16)x1.w;
                dst[u] = h;
            }
        }
    }
}

// reduce for TAIL=0 (nsplit atomic partials)
__global__ __launch_bounds__(256) void reduce_atomic_kernel(
    const float* __restrict__ partial,
    const float* __restrict__ cnt_partial,
    float* __restrict__ out_counts,
    float* __restrict__ out_sums,
    int nsplit)
{
    int idx = blockIdx.x * 256 + threadIdx.x;
    if (idx < K_CL * D) {
        float s = 0.f;
        for (int e = 0; e < nsplit; ++e) s += partial[(size_t)e * K_CL * D + idx];
        out_sums[idx] = s;
    } else if (idx < K_CL * D + K_CL) {
        int c = idx - K_CL * D;
        float s = 0.f;
        for (int e = 0; e < nsplit; ++e) s += cnt_partial[e * K_CL + c];
        out_counts[c] = s;
    }
}

// reduce for TAIL=2 (f32 store-all partials) and TAIL=1 (f16)
template<int TAIL>
__global__ __launch_bounds__(256) void reduce_store_kernel(
    const void* __restrict__ part,
    const float* __restrict__ cnt_partial,
    float* __restrict__ out_counts,
    float* __restrict__ out_sums)
{
    int idx = blockIdx.x * 256 + threadIdx.x;
    if (idx < K_CL * D) {
        float s = 0.f;
        if constexpr (TAIL == 2) {
            const float* p = (const float*)part;
            for (int b = 0; b < NBLK; ++b) s += p[(size_t)b * K_CL * D + idx];
        } else {
            const f16* p = (const f16*)part;
            for (int b = 0; b < NBLK; ++b) s += (float)p[(size_t)b * K_CL * D + idx];
        }
        out_sums[idx] = s;
    } else if (idx < K_CL * D + K_CL) {
        int c = idx - K_CL * D;
        float s = 0.f;
        for (int b = 0; b < NBLK; ++b) s += cnt_partial[(size_t)b * K_CL + c];
        out_counts[c] = s;
    }
}

extern "C" void kernel_launch(void* const* d_in, const int* in_sizes, int n_in,
                              void* d_out, int out_size, void* d_ws, size_t ws_size,
                              hipStream_t stream) {
    const float* batch = (const float*)d_in[0];
    const float* cent  = (const float*)d_in[1];
    float* out        = (float*)d_out;
    float* out_assign = out;
    float* out_counts = out + N_PTS;
    float* out_sums   = out + N_PTS + K_CL;

    char* ws = (char*)d_ws;
    float* csq    = (float*)ws;                         // 4 KB
    float* csqhn  = (float*)(ws + 4096);                // 4 KB
    f16*   cent16 = (f16*)(ws + 8192);                  // 128 KB
    char*  part   = ws + 8192 + 131072;

    const size_t base_need = 8192 + 131072;
    const size_t cnt_bytes = (size_t)NBLK * K_CL * 4;                       // 1 MB
    const size_t need_f32  = base_need + (size_t)NBLK * K_CL * D * 4 + cnt_bytes;  // ~65.2 MB
    const size_t need_f16  = base_need + (size_t)NBLK * K_CL * D * 2 + cnt_bytes;  // ~34.8 MB

    prep_kernel<<<K_CL / 256, 256, 0, stream>>>(cent, csq, csqhn, cent16);

    if (ws_size >= need_f32) {
        float* cnts = (float*)(part + (size_t)NBLK * K_CL * D * 4);
        assign_kernel<2><<<NBLK, 1024, 0, stream>>>(
            batch, cent16, csq, csqhn, cent, out_assign, part, cnts, 0);
        reduce_store_kernel<2><<<(K_CL * D + K_CL + 255) / 256, 256, 0, stream>>>(
            part, cnts, out_counts, out_sums);
    } else if (ws_size >= need_f16) {
        float* cnts = (float*)(part + (size_t)NBLK * K_CL * D * 2);
        assign_kernel<1><<<NBLK, 1024, 0, stream>>>(
            batch, cent16, csq, csqhn, cent, out_assign, part, cnts, 0);
        reduce_store_kernel<1><<<(K_CL * D + K_CL + 255) / 256, 256, 0, stream>>>(
            part, cnts, out_counts, out_sums);
    } else {
        // round-11 proven path: atomic nsplit partials
        int nsplit = 0;
        for (int ns = 32; ns >= 2; ns >>= 1) {
            size_t need = base_need + (size_t)ns * K_CL * D * 4 + (size_t)ns * K_CL * 4;
            if (ws_size >= need) { nsplit = ns; break; }
        }
        if (nsplit > 0) {
            float* cnts = (float*)(part + (size_t)nsplit * K_CL * D * 4);
            (void)hipMemsetAsync(part, 0,
                    (size_t)nsplit * K_CL * D * 4 + (size_t)nsplit * K_CL * 4, stream);
            assign_kernel<0><<<NBLK, 1024, 0, stream>>>(
                batch, cent16, csq, csqhn, cent, out_assign, part, cnts, nsplit - 1);
            reduce_atomic_kernel<<<(K_CL * D + K_CL + 255) / 256, 256, 0, stream>>>(
                (float*)part, cnts, out_counts, out_sums, nsplit);
        } else {
            (void)hipMemsetAsync(out_counts, 0, (size_t)(K_CL + K_CL * D) * sizeof(float), stream);
            assign_kernel<0><<<NBLK, 1024, 0, stream>>>(
                batch, cent16, csq, csqhn, cent, out_assign, out_sums, out_counts, 0);
        }
    }
}